// Round 3
// baseline (2288.354 us; speedup 1.0000x reference)
//
#include <hip/hip_runtime.h>

#define NTT 200
#define NXX 256
#define NB  128
#define NGC 12
#define DTF  (1.0f/199.0f)
#define IDTF 199.0f

typedef float f4 __attribute__((ext_vector_type(4)));

// ======================= device-side matrix construction =======================
// B = I - c*A is tridiagonal (+rank-2 periodic corners). Columns of B^-1 via
// fp64 Thomas solves; periodic corners via Woodbury rank-2 correction.
// TRANSPOSED device layout: MT[j*256+k] = Binv[j][k], so thread j's weights
// (y_new[j] = sum_k z[k] * Binv[j][k]) are CONTIGUOUS (dwordx4-loadable).

__global__ void k_mats1(double* __restrict__ Gd, float* __restrict__ MTd) {
    const double c = 65025.0 / 199.0;           // eps*dt/dx^2
    const double bd = 1.0 + 2.0 * c, a = -c;    // diag, offdiag of I - c*tri
    __shared__ double cp[256], invd[256];
    int tid = threadIdx.x;
    if (tid == 0) {
        double prev = 0.0;
        for (int i = 0; i < 256; i++) {
            double den = bd - a * prev;
            double ci = a / den;
            cp[i] = ci; invd[i] = 1.0 / den; prev = ci;
        }
    }
    __syncthreads();
    double x[256];
    if (tid < 256) {
        // periodic base T0 (pure tridiag, symmetric): column tid of G = T0^-1
        int jc = tid;
        double dp = 0.0;
        for (int i = 0; i < 256; i++) {
            double r = (i == jc) ? 1.0 : 0.0;
            dp = (r - a * dp) * invd[i];
            x[i] = dp;
        }
        for (int i = 254; i >= 0; i--) x[i] -= cp[i] * x[i + 1];
        for (int i = 0; i < 256; i++) Gd[jc * 256 + i] = x[i];
    } else {
        // Dirichlet: B_D = blockdiag(1, S, 1); S symmetric -> Binv symmetric,
        // so row jc equals column jc. Write transposed row MTd[jc][k].
        int jc = tid - 256;
        if (jc == 0 || jc == 255) {
            for (int k = 0; k < 256; k++) MTd[jc * 256 + k] = (k == jc) ? 1.f : 0.f;
        } else {
            int n = 254, jj = jc - 1;
            double dp = 0.0;
            for (int i = 0; i < n; i++) {
                double r = (i == jj) ? 1.0 : 0.0;
                dp = (r - a * dp) * invd[i];
                x[i] = dp;
            }
            for (int i = n - 2; i >= 0; i--) x[i] -= cp[i] * x[i + 1];
            MTd[jc * 256 + 0] = 0.f; MTd[jc * 256 + 255] = 0.f;
            for (int k = 1; k < 255; k++) MTd[jc * 256 + k] = (float)x[k - 1];
        }
    }
}

// j = blockIdx (row of Binv), k = threadIdx (col) -> coalesced loads+stores.
__global__ void k_mats2(const double* __restrict__ Gd, float* __restrict__ MTper) {
    const double c = 65025.0 / 199.0;
    int j = blockIdx.x, k = threadIdx.x;
    double G1_255 = Gd[256 + 255],         G1_0 = Gd[256 + 0];
    double G254_255 = Gd[254 * 256 + 255], G254_0 = Gd[254 * 256 + 0];
    double K00 = 1.0 - c * G1_255, K01 = -c * G1_0;
    double K10 = -c * G254_255,    K11 = 1.0 - c * G254_0;
    double id = 1.0 / (K00 * K11 - K01 * K10);
    double Ki00 = K11 * id, Ki01 = -K01 * id, Ki10 = -K10 * id, Ki11 = K00 * id;
    double g1k = Gd[256 + k], g254k = Gd[254 * 256 + k];
    double gjk = Gd[j * 256 + k], gj255 = Gd[j * 256 + 255], gj0 = Gd[j * 256 + 0];
    double corr = c * (gj255 * (Ki00 * g1k + Ki01 * g254k) +
                       gj0   * (Ki10 * g1k + Ki11 * g254k));
    MTper[j * 256 + k] = (float)(gjk + corr);
}

// ======================= forcing terms =======================
template<bool CONT>
__device__ __forceinline__ float forcing(int node, const float* __restrict__ W,
                                         const float* __restrict__ cont,
                                         const float* __restrict__ out,
                                         int b, int i, int j) {
    int widx = (b * NTT + i) * NXX + j;
    float dw;
    if (CONT) {
        size_t cb = (size_t)b * NTT * NXX + (size_t)i * NXX + j;
        const size_t CS = (size_t)NB * NTT * NXX;
        switch (node) {
            case 2:  return (W[widx] - W[widx - NXX]) * IDTF;
            case 4:  dw = (W[widx] - W[widx - NXX]) * IDTF; return dw * dw;
            case 3:  return cont[cb];                              // ic (slot0)
            case 5:  dw = (W[widx] - W[widx - NXX]) * IDTF; return dw * cont[cb];
            case 6:  { float f = cont[CS + cb]; return f * f; }    // f2 (slot1)
            case 7:  return cont[CS + cb] * cont[cb];
            case 8:  { float f = cont[CS + cb]; return f * f * f; }
            case 9:  dw = (W[widx] - W[widx - NXX]) * IDTF; return dw * cont[CS + cb];
            case 10: { float f = cont[cb]; return f * f; }
            default: return cont[3 * CS + cb] * cont[CS + cb];     // f4*f2
        }
    } else {
        size_t ob = (size_t)widx * NGC;
        switch (node) {
            case 2:  return (W[widx] - W[widx - NXX]) * IDTF;
            case 4:  dw = (W[widx] - W[widx - NXX]) * IDTF; return dw * dw;
            case 3:  return out[ob + 1];
            case 5:  dw = (W[widx] - W[widx - NXX]) * IDTF; return dw * out[ob + 1];
            case 6:  { float f = out[ob + 2]; return f * f; }
            case 7:  return out[ob + 2] * out[ob + 1];
            case 8:  { float f = out[ob + 2]; return f * f * f; }
            case 9:  dw = (W[widx] - W[widx - NXX]) * IDTF; return dw * out[ob + 2];
            case 10: { float f = out[ob + 1]; return f * f; }
            default: return out[ob + 4] * out[ob + 2];
        }
    }
}

// ======================= scan kernel =======================
// 512 threads. Lane pair (h = tid&1) splits column j = tid>>1 over K-halves;
// partial sums combine via shfl_xor(1). m-half pinned in VGPRs via volatile
// asm dwordx4 loads from the TRANSPOSED matrix. z double-buffered in LDS ->
// one barrier/step. Epilogue (forcing, store, z-update) split by g-parity.
template<int GROUP, int PHASE, bool CONT>
__global__ __launch_bounds__(512, 2) void k_scan(const float* __restrict__ W,
        const float* __restrict__ U0, const float* __restrict__ Mws,
        float* __restrict__ out, float* __restrict__ cont) {
    int node;
    if (PHASE == 0) { const int L[3] = {1, 2, 4}; node = L[blockIdx.y]; }
    else            { const int L[8] = {3, 5, 6, 7, 8, 9, 10, 11}; node = L[blockIdx.y]; }
    const float* MT = (node == 1) ? (Mws + 65536) : Mws;   // ic uses Dirichlet
    const int b0 = blockIdx.x * GROUP;
    const int tid = threadIdx.x;
    const int h = tid & 1, j = tid >> 1;

    // 128 contiguous column weights: MT[j*256 + h*128 .. +127], held in VGPRs
    const float* mb = MT + j * 256 + h * 128;
    f4 mv[32];
#pragma unroll
    for (int q = 0; q < 32; q++)
        asm volatile("global_load_dwordx4 %0, %1, off offset:%2"
                     : "=v"(mv[q]) : "v"(mb), "i"(q * 16));
    asm volatile("s_waitcnt vmcnt(0)" ::: "memory");

    __shared__ __align__(16) float zb[2][GROUP][256];

    // init state z_0 (= f_1*dt, or U0 for ic); lane handles g with (g&1)==h
#pragma unroll
    for (int g = h; g < GROUP; g += 2) {
        float v;
        if (node == 1) v = U0[(b0 + g) * 256 + j];
        else           v = forcing<CONT>(node, W, cont, out, b0 + g, 1, j) * DTF;
        zb[0][g][j] = v;
    }
    __syncthreads();

#define STEP(I, PIN, POUT, LAST)                                              \
    {                                                                         \
        float tn[GROUP];                                                      \
        _Pragma("unroll")                                                     \
        for (int g = 0; g < GROUP; g++) tn[g] = 0.f;                          \
        if (!(LAST) && node != 1) {                                           \
            _Pragma("unroll")                                                 \
            for (int g = h; g < GROUP; g += 2)                                \
                tn[g] = forcing<CONT>(node, W, cont, out, b0 + g, (I) + 1, j);\
        }                                                                     \
        float acc[GROUP];                                                     \
        _Pragma("unroll")                                                     \
        for (int g = 0; g < GROUP; g++) acc[g] = 0.f;                         \
        _Pragma("unroll")                                                     \
        for (int q = 0; q < 32; q++) {                                        \
            _Pragma("unroll")                                                 \
            for (int g = 0; g < GROUP; g++) {                                 \
                f4 zz = *(const f4*)&zb[PIN][g][h * 128 + q * 4];             \
                acc[g] = fmaf(mv[q].x, zz.x, acc[g]);                         \
                acc[g] = fmaf(mv[q].y, zz.y, acc[g]);                         \
                acc[g] = fmaf(mv[q].z, zz.z, acc[g]);                         \
                acc[g] = fmaf(mv[q].w, zz.w, acc[g]);                         \
            }                                                                 \
        }                                                                     \
        _Pragma("unroll")                                                     \
        for (int g = 0; g < GROUP; g++) acc[g] += __shfl_xor(acc[g], 1);      \
        _Pragma("unroll")                                                     \
        for (int g = h; g < GROUP; g += 2) {                                  \
            float y = acc[g];                                                 \
            if (CONT)                                                         \
                cont[(((size_t)(node - 1) * NB + (b0 + g)) * NTT + (I)) * NXX + j] = y; \
            else                                                              \
                out[((size_t)((b0 + g) * NTT + (I)) * NXX + j) * NGC + node] = y;       \
            if (!(LAST)) zb[POUT][g][j] = (node == 1) ? y : fmaf(tn[g], DTF, y);        \
        }                                                                     \
        if (!(LAST)) __syncthreads();                                         \
    }

    int i = 1;
    for (; i + 1 < NTT; i += 2) {        // i = 1,3,...,197  (steps 1..198)
        STEP(i, 0, 1, false);
        STEP(i + 1, 1, 0, false);
    }
    STEP(NTT - 1, 0, 1, true);           // step 199 reads buffer 0
#undef STEP
}

// ======================= output assembly (CONT path) =======================
__global__ void k_out(const float* __restrict__ W, const float* __restrict__ U0,
                      const float* __restrict__ cont, float* __restrict__ out) {
    int t = blockIdx.x, b = blockIdx.y, x = threadIdx.x;
    int idx = (b * NTT + t) * NXX + x;
    float v[12];
    float dw = 0.f;
    if (t) dw = (W[idx] - W[idx - NXX]) * IDTF;
    v[0] = dw;
    if (t) {
        size_t cb = (size_t)b * NTT * NXX + (size_t)t * NXX + x;
        const size_t CS = (size_t)NB * NTT * NXX;
#pragma unroll
        for (int n = 1; n < 12; n++) v[n] = cont[(size_t)(n - 1) * CS + cb];
    } else {
        v[1] = U0[b * NXX + x];
#pragma unroll
        for (int n = 2; n < 12; n++) v[n] = 0.f;
    }
    float4* o = (float4*)(out + (size_t)idx * 12);
    o[0] = make_float4(v[0], v[1], v[2], v[3]);
    o[1] = make_float4(v[4], v[5], v[6], v[7]);
    o[2] = make_float4(v[8], v[9], v[10], v[11]);
}

// fallback fill (non-CONT path)
__global__ void k_fill(const float* __restrict__ W, const float* __restrict__ U0,
                       float* __restrict__ out) {
    int tid = blockIdx.x * 256 + threadIdx.x;
    int x = tid & 255;
    int t = (tid >> 8) % NTT;
    int b = tid / (NXX * NTT);
    float dw = 0.f;
    if (t > 0) dw = (W[tid] - W[tid - NXX]) * IDTF;
    size_t ob = (size_t)tid * NGC;
    out[ob] = dw;
    if (t == 0) {
        out[ob + 1] = U0[b * 256 + x];
#pragma unroll
        for (int g = 2; g < 12; g++) out[ob + g] = 0.f;
    }
}

// ======================= launch =======================
extern "C" void kernel_launch(void* const* d_in, const int* in_sizes, int n_in,
                              void* d_out, int out_size, void* d_ws, size_t ws_size,
                              hipStream_t stream) {
    const float* W  = (const float*)d_in[0];
    const float* U0 = (const float*)d_in[1];
    float* out = (float*)d_out;

    double* Gd   = (double*)d_ws;                         // 512 KB fp64 T0^-1
    float*  MTper = (float*)((char*)d_ws + (512 << 10));  // 256 KB (transposed)
    float*  MTdir = (float*)((char*)d_ws + (768 << 10));  // 256 KB (= MTper+65536)
    float*  cont  = (float*)((char*)d_ws + (1 << 20));    // 11 * 26.2 MB

    size_t need = (size_t)(1 << 20) + 11ull * NB * NTT * NXX * 4;
    bool cont_ok = ws_size >= need;

    k_mats1<<<1, 512, 0, stream>>>(Gd, MTdir);
    k_mats2<<<256, 256, 0, stream>>>(Gd, MTper);

    if (cont_ok) {
        k_scan<2, 0, true><<<dim3(64, 3), 512, 0, stream>>>(W, U0, MTper, out, cont);
        k_scan<4, 1, true><<<dim3(32, 8), 512, 0, stream>>>(W, U0, MTper, out, cont);
        k_out<<<dim3(NTT, NB), 256, 0, stream>>>(W, U0, cont, out);
    } else {
        k_fill<<<NB * NTT, 256, 0, stream>>>(W, U0, out);
        k_scan<2, 0, false><<<dim3(64, 3), 512, 0, stream>>>(W, U0, MTper, out, cont);
        k_scan<4, 1, false><<<dim3(32, 8), 512, 0, stream>>>(W, U0, MTper, out, cont);
    }
}

// Round 4
// 472.007 us; speedup vs baseline: 4.8481x; 4.8481x over previous
//
#include <hip/hip_runtime.h>

#define IDTF 199.0f
#define DTF  (1.0f/199.0f)
#define LDSP 13

// ===================== PCR coefficient precompute (fp64) =====================
// B = I - c*A. m=0: T = truncated tridiag(-c,1+2c,-c) (periodic base, corners
// handled by Woodbury). m=1: B_D = blockdiag(1, S, 1) (Dirichlet).
// C rows (256 floats each):
//   m*17 + l      alpha[l]   (l=0..7)
//   m*17 + 8 + l  beta[l]
//   m*17 + 16     invd
//   34 / 35       PK columns: (T^-1 U) K^-1  (periodic Woodbury, rank 2)
__global__ void k_pcr(float* __restrict__ C) {
    const double cc = 65025.0 / 199.0;   // eps*dt/dx^2 = (255^2)/199
    __shared__ double a[2][256], b[2][256], c[2][256];
    int x = threadIdx.x;
    for (int m = 0; m < 2; m++) {
        double ai, bi, ci;
        if (m == 0) {
            ai = (x == 0) ? 0.0 : -cc;
            bi = 1.0 + 2.0 * cc;
            ci = (x == 255) ? 0.0 : -cc;
        } else {
            if (x == 0 || x == 255) { ai = 0.0; bi = 1.0; ci = 0.0; }
            else {
                ai = (x == 1) ? 0.0 : -cc;
                bi = 1.0 + 2.0 * cc;
                ci = (x == 254) ? 0.0 : -cc;
            }
        }
        int cur = 0;
        a[0][x] = ai; b[0][x] = bi; c[0][x] = ci;
        __syncthreads();
        for (int l = 0; l < 8; l++) {
            int s = 1 << l;
            int xm = (x - s < 0) ? 0 : x - s;
            int xp = (x + s > 255) ? 255 : x + s;
            double al = a[cur][x] / b[cur][xm];   // a==0 exactly when x-s<0
            double be = c[cur][x] / b[cur][xp];   // c==0 exactly when x+s>255
            C[(m * 17 + l) * 256 + x] = (float)al;
            C[(m * 17 + 8 + l) * 256 + x] = (float)be;
            double an = -al * a[cur][xm];
            double cn = -be * c[cur][xp];
            double bn = b[cur][x] - al * c[cur][xm] - be * a[cur][xp];
            a[1 - cur][x] = an; b[1 - cur][x] = bn; c[1 - cur][x] = cn;
            __syncthreads();
            cur = 1 - cur;
        }
        C[(m * 17 + 16) * 256 + x] = (float)(1.0 / b[cur][x]);
        __syncthreads();
    }
    if (x == 0) {
        // two fp64 Thomas solves on T: t1 = T^-1(-c e0), t2 = T^-1(-c e255)
        double cp[256], t1[256], t2[256];
        double bloc = 1.0 + 2.0 * cc;
        cp[0] = -cc / bloc;
        t1[0] = -cc / bloc;
        t2[0] = 0.0;
        for (int i = 1; i < 256; i++) {
            double den = bloc + cc * cp[i - 1];          // b - a*cp, a = -cc
            double ci2 = (i < 255) ? (-cc / den) : 0.0;
            double r1 = (cc * t1[i - 1]) / den;
            double r2 = (((i == 255) ? -cc : 0.0) + cc * t2[i - 1]) / den;
            cp[i] = ci2; t1[i] = r1; t2[i] = r2;
        }
        for (int i = 254; i >= 0; i--) {
            t1[i] -= cp[i] * t1[i + 1];
            t2[i] -= cp[i] * t2[i + 1];
        }
        // K = I + V^T (T^-1 U), V = [e254, e1]
        double K00 = 1.0 + t1[254], K01 = t2[254], K10 = t1[1], K11 = 1.0 + t2[1];
        double idet = 1.0 / (K00 * K11 - K01 * K10);
        double Ki00 = K11 * idet, Ki01 = -K01 * idet;
        double Ki10 = -K10 * idet, Ki11 = K00 * idet;
        for (int i = 0; i < 256; i++) {
            C[34 * 256 + i] = (float)(t1[i] * Ki00 + t2[i] * Ki10);
            C[35 * 256 + i] = (float)(t1[i] * Ki01 + t2[i] * Ki11);
        }
    }
}

// ===================== fused scan kernel =====================
__device__ __forceinline__ float bp(int idx, float v) {
    return __builtin_bit_cast(float,
        __builtin_amdgcn_ds_bpermute(idx, __builtin_bit_cast(int, v)));
}

// block = one batch b. 12 waves:
//  wv 0..2  producers: nodes 1(ic,Dirichlet), 2(f2,+writes dW->ch0), 4
//  wv 3..10 consumers: nodes 3,5,6,7,8,9,10,11 (lag 1 step)
//  wv 11    output assembly (lag 2 steps), coalesced dwordx4 stores
// ych triple-buffered: time t lives in buf t%3.
__global__ __launch_bounds__(768) void k_fused(const float* __restrict__ W,
        const float* __restrict__ U0, const float* __restrict__ C,
        float* __restrict__ out) {
    __shared__ float ych[3][256][LDSP];
    const int b = blockIdx.x;
    const int tid = threadIdx.x;
    const int wv = tid >> 6;
    const int L = tid & 63;

    if (wv == 11) {
        // ---------- output wave ----------
        int xk[12], rk[12];
#pragma unroll
        for (int k = 0; k < 12; k++) {
            int f = L + 64 * k;
            xk[k] = f / 3;
            rk[k] = f - 3 * xk[k];
        }
        float* obase = out + (size_t)b * 200 * 3072;
        for (int i = 1; i <= 201; i++) {
            int t = i - 2;
            if (t == 0) {
#pragma unroll
                for (int k = 0; k < 12; k++) {
                    float4 v = make_float4(0.f, 0.f, 0.f, 0.f);
                    if (rk[k] == 0) v.y = U0[b * 256 + xk[k]];
                    *(float4*)(obase + (size_t)t * 3072 + (L + 64 * k) * 4) = v;
                }
            } else if (t >= 1) {
                const float* lb = &ych[t % 3][0][0];
#pragma unroll
                for (int k = 0; k < 12; k++) {
                    const float* p = lb + xk[k] * LDSP + rk[k] * 4;
                    float4 v = make_float4(p[0], p[1], p[2], p[3]);
                    *(float4*)(obase + (size_t)t * 3072 + (L + 64 * k) * 4) = v;
                }
            }
            __syncthreads();
        }
    } else {
        // ---------- solver waves ----------
        const int NODE[11] = {1, 2, 4, 3, 5, 6, 7, 8, 9, 10, 11};
        // consumer forcing encodings (index wv-3): f from channels ca, cb
        const int CA[8] = {1, 0, 2, 2, 2, 0, 1, 4};
        const int CB[8] = {1, 1, 2, 1, 2, 2, 1, 2};
        const int MODE[8] = {0, 1, 1, 1, 2, 1, 1, 1};   // 0=copy,1=mul,2=cube
        const int node = NODE[wv];
        const bool isIC = (node == 1);
        const bool needW = (node == 2 || node == 4);
        const bool isProd = (node == 1 || node == 2 || node == 4);
        const int mat = isIC ? 1 : 0;
        int ca = 0, cb = 0, mode = 0;
        if (!isProd) { ca = CA[wv - 3]; cb = CB[wv - 3]; mode = MODE[wv - 3]; }

        // coefficients -> registers (negated for fmaf)
        float nal[8][4], nbe[8][4], ivd[4], npk0[4], npk1[4];
#pragma unroll
        for (int q = 0; q < 4; q++) {
            int x = L + 64 * q;
#pragma unroll
            for (int l = 0; l < 8; l++) {
                nal[l][q] = -C[(mat * 17 + l) * 256 + x];
                nbe[l][q] = -C[(mat * 17 + 8 + l) * 256 + x];
            }
            ivd[q] = C[(mat * 17 + 16) * 256 + x];
            npk0[q] = -C[34 * 256 + x];
            npk1[q] = -C[35 * 256 + x];
        }
        int ism[6], isp[6];
#pragma unroll
        for (int l = 0; l < 6; l++) {
            int s = 1 << l;
            ism[l] = ((L - s) & 63) << 2;
            isp[l] = ((L + s) & 63) << 2;
        }

        float y[4] = {0.f, 0.f, 0.f, 0.f};
        float wprev[4], wcur[4], wnxt[4];
        if (isIC) {
#pragma unroll
            for (int q = 0; q < 4; q++) y[q] = U0[b * 256 + L + 64 * q];
        }
        if (needW) {
#pragma unroll
            for (int q = 0; q < 4; q++) {
                wprev[q] = W[((size_t)b * 200 + 0) * 256 + L + 64 * q];
                wcur[q]  = W[((size_t)b * 200 + 1) * 256 + L + 64 * q];
            }
        }

        for (int i = 1; i <= 201; i++) {
            const int t = isProd ? i : (i - 1);
            const bool active = isProd ? (i <= 199) : (i >= 2 && i <= 200);
            if (active) {
                const int tb = t % 3;
                // ----- forcing -----
                float d[4];
                if (isIC) {
#pragma unroll
                    for (int q = 0; q < 4; q++) d[q] = y[q];
                } else if (needW) {
                    float dw[4];
#pragma unroll
                    for (int q = 0; q < 4; q++) {
                        dw[q] = (wcur[q] - wprev[q]) * IDTF;
                        wprev[q] = wcur[q];
                    }
                    if (t <= 198) {
#pragma unroll
                        for (int q = 0; q < 4; q++)
                            wnxt[q] = W[((size_t)b * 200 + t + 1) * 256 + L + 64 * q];
                    }
                    if (node == 2) {
#pragma unroll
                        for (int q = 0; q < 4; q++) {
                            ych[tb][L + 64 * q][0] = dw[q];          // publish dW
                            d[q] = fmaf(dw[q], DTF, y[q]);
                        }
                    } else {
#pragma unroll
                        for (int q = 0; q < 4; q++)
                            d[q] = fmaf(dw[q] * dw[q], DTF, y[q]);
                    }
                } else {
                    const float* lb = &ych[t % 3][0][0];
#pragma unroll
                    for (int q = 0; q < 4; q++) {
                        int xb = (L + 64 * q) * LDSP;
                        float u = lb[xb + ca];
                        float v = lb[xb + cb];
                        float t2 = u * v;
                        float fq = (mode == 0) ? u : ((mode == 2) ? t2 * u : t2);
                        d[q] = fmaf(fq, DTF, y[q]);
                    }
                }
                // ----- PCR solve: B d_new = d -----
#pragma unroll
                for (int l = 0; l < 6; l++) {
                    int s = 1 << l;
                    float A0 = bp(ism[l], d[0]), A1 = bp(ism[l], d[1]);
                    float A2 = bp(ism[l], d[2]), A3 = bp(ism[l], d[3]);
                    float B0 = bp(isp[l], d[0]), B1 = bp(isp[l], d[1]);
                    float B2 = bp(isp[l], d[2]), B3 = bp(isp[l], d[3]);
                    bool lo = (L >= s), hi = (L + s < 64);
                    float m0 = A0;
                    float m1 = lo ? A1 : A0;
                    float m2 = lo ? A2 : A1;
                    float m3 = lo ? A3 : A2;
                    float p0 = hi ? B0 : B1;
                    float p1 = hi ? B1 : B2;
                    float p2 = hi ? B2 : B3;
                    float p3 = B3;
                    d[0] = fmaf(nal[l][0], m0, fmaf(nbe[l][0], p0, d[0]));
                    d[1] = fmaf(nal[l][1], m1, fmaf(nbe[l][1], p1, d[1]));
                    d[2] = fmaf(nal[l][2], m2, fmaf(nbe[l][2], p2, d[2]));
                    d[3] = fmaf(nal[l][3], m3, fmaf(nbe[l][3], p3, d[3]));
                }
                {   // s = 64 (register level; alpha[6][0]=beta[6][3]=0)
                    float e0 = fmaf(nbe[6][0], d[1], d[0]);
                    float e1 = fmaf(nal[6][1], d[0], fmaf(nbe[6][1], d[2], d[1]));
                    float e2 = fmaf(nal[6][2], d[1], fmaf(nbe[6][2], d[3], d[2]));
                    float e3 = fmaf(nal[6][3], d[2], d[3]);
                    d[0] = e0; d[1] = e1; d[2] = e2; d[3] = e3;
                }
                {   // s = 128 (alpha[7][0..1]=beta[7][2..3]=0)
                    float e0 = fmaf(nbe[7][0], d[2], d[0]);
                    float e1 = fmaf(nbe[7][1], d[3], d[1]);
                    float e2 = fmaf(nal[7][2], d[0], d[2]);
                    float e3 = fmaf(nal[7][3], d[1], d[3]);
                    d[0] = e0; d[1] = e1; d[2] = e2; d[3] = e3;
                }
#pragma unroll
                for (int q = 0; q < 4; q++) d[q] *= ivd[q];
                if (!isIC) {   // Woodbury rank-2 periodic correction
                    float s1 = __shfl(d[3], 62, 64);   // w[254]
                    float s2 = __shfl(d[0], 1, 64);    // w[1]
#pragma unroll
                    for (int q = 0; q < 4; q++)
                        d[q] = fmaf(npk0[q], s1, fmaf(npk1[q], s2, d[q]));
                }
#pragma unroll
                for (int q = 0; q < 4; q++) {
                    y[q] = d[q];
                    ych[tb][L + 64 * q][node] = d[q];
                }
                if (needW && t <= 198) {
#pragma unroll
                    for (int q = 0; q < 4; q++) wcur[q] = wnxt[q];
                }
            }
            __syncthreads();
        }
    }
}

// ===================== launch =====================
extern "C" void kernel_launch(void* const* d_in, const int* in_sizes, int n_in,
                              void* d_out, int out_size, void* d_ws, size_t ws_size,
                              hipStream_t stream) {
    const float* W = (const float*)d_in[0];
    const float* U0 = (const float*)d_in[1];
    float* out = (float*)d_out;
    float* C = (float*)d_ws;   // 36*256 floats = 36 KB

    k_pcr<<<1, 256, 0, stream>>>(C);
    k_fused<<<128, 768, 0, stream>>>(W, U0, C, out);
}

// Round 5
// 443.870 us; speedup vs baseline: 5.1555x; 1.0634x over previous
//
#include <hip/hip_runtime.h>

#define IDTF 199.0f
#define DTF  (1.0f/199.0f)

typedef float f4 __attribute__((ext_vector_type(4)));

// ===================== PCR coefficient precompute (fp64) =====================
// B = I - c*A. m=0: truncated tridiag (periodic base; corners via Woodbury).
// m=1: Dirichlet blockdiag(1, S, 1).
// C rows (256 floats): m*17+l: alpha[l] (l=0..7); m*17+8+l: beta[l];
// m*17+16: invd; rows 34/35: (T^-1 U) K^-1 Woodbury columns.
__global__ void k_pcr(float* __restrict__ C) {
    const double cc = 65025.0 / 199.0;   // eps*dt/dx^2 = 255^2/199
    __shared__ double a[2][256], b[2][256], c[2][256];
    int x = threadIdx.x;
    for (int m = 0; m < 2; m++) {
        double ai, bi, ci;
        if (m == 0) {
            ai = (x == 0) ? 0.0 : -cc;
            bi = 1.0 + 2.0 * cc;
            ci = (x == 255) ? 0.0 : -cc;
        } else {
            if (x == 0 || x == 255) { ai = 0.0; bi = 1.0; ci = 0.0; }
            else {
                ai = (x == 1) ? 0.0 : -cc;
                bi = 1.0 + 2.0 * cc;
                ci = (x == 254) ? 0.0 : -cc;
            }
        }
        int cur = 0;
        a[0][x] = ai; b[0][x] = bi; c[0][x] = ci;
        __syncthreads();
        for (int l = 0; l < 8; l++) {
            int s = 1 << l;
            int xm = (x - s < 0) ? 0 : x - s;
            int xp = (x + s > 255) ? 255 : x + s;
            double al = a[cur][x] / b[cur][xm];   // a==0 exactly when x-s<0
            double be = c[cur][x] / b[cur][xp];   // c==0 exactly when x+s>255
            C[(m * 17 + l) * 256 + x] = (float)al;
            C[(m * 17 + 8 + l) * 256 + x] = (float)be;
            double an = -al * a[cur][xm];
            double cn = -be * c[cur][xp];
            double bn = b[cur][x] - al * c[cur][xm] - be * a[cur][xp];
            a[1 - cur][x] = an; b[1 - cur][x] = bn; c[1 - cur][x] = cn;
            __syncthreads();
            cur = 1 - cur;
        }
        C[(m * 17 + 16) * 256 + x] = (float)(1.0 / b[cur][x]);
        __syncthreads();
    }
    if (x == 0) {
        // Thomas solves on T: t1 = T^-1(-c e0), t2 = T^-1(-c e255), 1 div/iter
        double cp[256], t1[256], t2[256];
        double bloc = 1.0 + 2.0 * cc;
        double inv0 = 1.0 / bloc;
        cp[0] = -cc * inv0;
        t1[0] = -cc * inv0;
        t2[0] = 0.0;
        for (int i = 1; i < 256; i++) {
            double den = bloc + cc * cp[i - 1];   // b - a*cp, a=-cc
            double invd = 1.0 / den;
            cp[i] = (i < 255) ? (-cc * invd) : 0.0;
            t1[i] = (cc * t1[i - 1]) * invd;
            t2[i] = (((i == 255) ? -cc : 0.0) + cc * t2[i - 1]) * invd;
        }
        for (int i = 254; i >= 0; i--) {
            t1[i] -= cp[i] * t1[i + 1];
            t2[i] -= cp[i] * t2[i + 1];
        }
        double K00 = 1.0 + t1[254], K01 = t2[254], K10 = t1[1], K11 = 1.0 + t2[1];
        double idet = 1.0 / (K00 * K11 - K01 * K10);
        double Ki00 = K11 * idet, Ki01 = -K01 * idet;
        double Ki10 = -K10 * idet, Ki11 = K00 * idet;
        for (int i = 0; i < 256; i++) {
            C[34 * 256 + i] = (float)(t1[i] * Ki00 + t2[i] * Ki10);
            C[35 * 256 + i] = (float)(t1[i] * Ki01 + t2[i] * Ki11);
        }
    }
}

// ===================== split scan kernel =====================
__device__ __forceinline__ float bp(int idx, float v) {
    return __builtin_bit_cast(float,
        __builtin_amdgcn_ds_bpermute(idx, __builtin_bit_cast(int, v)));
}

// grid (128 batches, 2 roles), 384 threads = 6 waves; lane L owns x=4L..4L+3.
// role 0: waves = nodes {1(ic,Dirichlet), 2*(shadow f2, stores ch0=dW), 3, 5, 7, 10}
// role 1: waves = nodes {2, 4, 6, 8, 9, 11}
// ychv planar double-buffer: [parity][plane][64] f4; plane0/1 per role.
__global__ __launch_bounds__(384) void k_split(const float* __restrict__ W,
        const float* __restrict__ U0, const float* __restrict__ C,
        float* __restrict__ out) {
    const int b = blockIdx.x;
    const int role = blockIdx.y;
    const int tid = threadIdx.x;
    const int wv = tid >> 6;
    const int L = tid & 63;

    const bool isIC = (role == 0 && wv == 0);
    const bool isProd = (wv < 2);
    const bool storeDW = (role == 0 && wv == 1);
    bool needW;
    int storeCh, pubPlane, fmode, pmode;
    if (role == 0) {
        const int SC[6] = {1, 0, 3, 5, 7, 10};
        const int FM[6] = {-1, -1, 0, 1, 2, 3};   // p0 | dW*p0 | p1*p0 | p0^2
        storeCh = SC[wv]; fmode = FM[wv];
        needW = (wv == 1 || wv == 3);
        pubPlane = (wv == 0) ? 0 : ((wv == 1) ? 1 : -1);
        pmode = (wv == 0) ? 0 : 1;                // ic: d=y ; 2*: d=y+dW*dt
    } else {
        const int SC[6] = {2, 4, 6, 8, 9, 11};
        const int FM[6] = {-1, -1, 3, 4, 1, 2};   // p0^2 | p0^3 | dW*p0 | p1*p0
        storeCh = SC[wv]; fmode = FM[wv];
        needW = (wv <= 1 || wv == 4);
        pubPlane = (wv <= 1) ? wv : -1;
        pmode = (wv == 0) ? 1 : 2;                // 2: dW ; 4: dW^2
    }
    const int mat = isIC ? 1 : 0;

    // ---- coefficients into registers (negated for fmaf) ----
    const float* Cm = C + mat * 17 * 256;
    float nal[8][4], nbe[8][4], ivd4[4], npk0[4], npk1[4];
#pragma unroll
    for (int l = 0; l < 8; l++) {
        f4 va = *(const f4*)&Cm[l * 256 + 4 * L];
        f4 vb = *(const f4*)&Cm[(8 + l) * 256 + 4 * L];
#pragma unroll
        for (int q = 0; q < 4; q++) { nal[l][q] = -va[q]; nbe[l][q] = -vb[q]; }
    }
    {
        f4 vd = *(const f4*)&Cm[16 * 256 + 4 * L];
        f4 p0 = *(const f4*)&C[34 * 256 + 4 * L];
        f4 p1 = *(const f4*)&C[35 * 256 + 4 * L];
#pragma unroll
        for (int q = 0; q < 4; q++) { ivd4[q] = vd[q]; npk0[q] = -p0[q]; npk1[q] = -p1[q]; }
    }

    __shared__ f4 ychv[2][2][64];
    __shared__ f4 scr[6][64];

    // ---- state init + t=0 output row ----
    float y[4] = {0.f, 0.f, 0.f, 0.f};
    if (isIC) {
        f4 u0 = *(const f4*)&U0[b * 256 + 4 * L];
#pragma unroll
        for (int q = 0; q < 4; q++) y[q] = u0[q];
    }
    {
        size_t ob = ((size_t)b * 200) * 3072 + storeCh;
#pragma unroll
        for (int q = 0; q < 4; q++) out[ob + (4 * L + q) * 12] = isIC ? y[q] : 0.f;
    }
    float wprev[4] = {0,0,0,0}, wcur[4] = {0,0,0,0}, wnxt[4] = {0,0,0,0};
    if (needW) {
        f4 w0 = *(const f4*)&W[((size_t)b * 200 + 0) * 256 + 4 * L];
        f4 w1 = *(const f4*)&W[((size_t)b * 200 + 1) * 256 + 4 * L];
#pragma unroll
        for (int q = 0; q < 4; q++) { wprev[q] = w0[q]; wcur[q] = w1[q]; }
    }
    __syncthreads();

#define LVL(l) _Pragma("unroll") for (int q = 0; q < 4; q++) \
        d[q] = fmaf(nal[l][q], mm[q], fmaf(nbe[l][q], pp[q], d[q]));

    for (int i = 1; i <= 200; i++) {
        bool active = isProd ? (i <= 199) : (i >= 2);
        if (active) {
            const int t = isProd ? i : (i - 1);
            float dwv[4] = {0,0,0,0};
            if (needW) {
#pragma unroll
                for (int q = 0; q < 4; q++) dwv[q] = (wcur[q] - wprev[q]) * IDTF;
                if (t <= 198) {
                    f4 wn = *(const f4*)&W[((size_t)b * 200 + t + 1) * 256 + 4 * L];
#pragma unroll
                    for (int q = 0; q < 4; q++) wnxt[q] = wn[q];
                }
            }
            // ---- forcing ----
            float d[4];
            if (isProd) {
                if (pmode == 0) {
#pragma unroll
                    for (int q = 0; q < 4; q++) d[q] = y[q];
                } else if (pmode == 1) {
#pragma unroll
                    for (int q = 0; q < 4; q++) d[q] = fmaf(dwv[q], DTF, y[q]);
                } else {
#pragma unroll
                    for (int q = 0; q < 4; q++) d[q] = fmaf(dwv[q] * dwv[q], DTF, y[q]);
                }
            } else {
                f4 u = ychv[(i - 1) & 1][0][L];
                f4 v = (fmode == 2) ? ychv[(i - 1) & 1][1][L] : u;
#pragma unroll
                for (int q = 0; q < 4; q++) {
                    float fq;
                    if (fmode == 0)      fq = u[q];
                    else if (fmode == 1) fq = dwv[q] * u[q];
                    else if (fmode == 2) fq = v[q] * u[q];
                    else if (fmode == 3) fq = u[q] * u[q];
                    else                 fq = u[q] * u[q] * u[q];
                    d[q] = fmaf(fq, DTF, y[q]);
                }
            }
            // ---- PCR solve: B d_new = d ----
            {   // s = 1
                float am = bp(((L + 63) & 63) << 2, d[3]);
                float ap = bp(((L + 1) & 63) << 2, d[0]);
                float mm[4] = {am, d[0], d[1], d[2]};
                float pp[4] = {d[1], d[2], d[3], ap};
                LVL(0)
            }
            {   // s = 2
                int im = ((L + 63) & 63) << 2, ip = ((L + 1) & 63) << 2;
                float m0 = bp(im, d[2]), m1 = bp(im, d[3]);
                float p2 = bp(ip, d[0]), p3 = bp(ip, d[1]);
                float mm[4] = {m0, m1, d[0], d[1]};
                float pp[4] = {d[2], d[3], p2, p3};
                LVL(1)
            }
#pragma unroll
            for (int l = 2; l < 8; l++) {   // s = 4,8,16,32,64,128 ; sig lanes
                const int sig = 1 << (l - 2);
                __builtin_amdgcn_wave_barrier();
                f4 pk; pk[0] = d[0]; pk[1] = d[1]; pk[2] = d[2]; pk[3] = d[3];
                scr[wv][L] = pk;
                __builtin_amdgcn_wave_barrier();
                f4 vm = scr[wv][(L - sig) & 63];
                f4 vp = (sig == 32) ? vm : scr[wv][(L + sig) & 63];
                __builtin_amdgcn_wave_barrier();
                float mm[4] = {vm[0], vm[1], vm[2], vm[3]};
                float pp[4] = {vp[0], vp[1], vp[2], vp[3]};
                LVL(l)
            }
#pragma unroll
            for (int q = 0; q < 4; q++) d[q] *= ivd4[q];
            if (!isIC) {   // periodic Woodbury rank-2 correction
                float s1 = __shfl(d[2], 63, 64);   // w[254] = 4*63+2
                float s2 = __shfl(d[1], 0, 64);    // w[1]
#pragma unroll
                for (int q = 0; q < 4; q++)
                    d[q] = fmaf(npk0[q], s1, fmaf(npk1[q], s2, d[q]));
            }
#pragma unroll
            for (int q = 0; q < 4; q++) y[q] = d[q];
            // ---- publish / store ----
            if (pubPlane >= 0) {
                f4 pk; pk[0] = y[0]; pk[1] = y[1]; pk[2] = y[2]; pk[3] = y[3];
                ychv[i & 1][pubPlane][L] = pk;
            }
            {
                size_t ob = ((size_t)b * 200 + t) * 3072 + storeCh;
#pragma unroll
                for (int q = 0; q < 4; q++)
                    out[ob + (4 * L + q) * 12] = storeDW ? dwv[q] : y[q];
            }
            if (needW && t <= 198) {
#pragma unroll
                for (int q = 0; q < 4; q++) { wprev[q] = wcur[q]; wcur[q] = wnxt[q]; }
            }
        }
        __syncthreads();
    }
#undef LVL
}

// ===================== launch =====================
extern "C" void kernel_launch(void* const* d_in, const int* in_sizes, int n_in,
                              void* d_out, int out_size, void* d_ws, size_t ws_size,
                              hipStream_t stream) {
    const float* W = (const float*)d_in[0];
    const float* U0 = (const float*)d_in[1];
    float* out = (float*)d_out;
    float* C = (float*)d_ws;   // 36*256 floats = 36 KB

    k_pcr<<<1, 256, 0, stream>>>(C);
    k_split<<<dim3(128, 2), 384, 0, stream>>>(W, U0, C, out);
}

// Round 7
// 423.532 us; speedup vs baseline: 5.4030x; 1.0480x over previous
//
#include <hip/hip_runtime.h>

#define IDTF 199.0f
#define DTF  (1.0f/199.0f)
#define KLAG 8
#define RING 16

typedef float f4 __attribute__((ext_vector_type(4)));

// ===================== PCR coefficient precompute (fp64) =====================
// B = I - c*A. m=0: truncated tridiag (periodic base; corners via Woodbury).
// m=1: Dirichlet blockdiag(1, S, 1).
// Fused 2-level PCR coefficients. C layout (rows of 256 floats), per m at
// m*22: rows p*6+{0..5} = A3,A2,A1,B1,B2,B3 for stage p in {0,1,2} (s=1,4,16);
// rows 18,19,20 = combined stage-3 (s=64): cM(-16 lanes), cC(+-32), cP(+16);
// row 21 = invd. Rows 44,45: Woodbury (T^-1 U) K^-1 columns.
__global__ void k_pcr(float* __restrict__ C) {
    const double cc = 65025.0 / 199.0;   // eps*dt/dx^2 = 255^2/199
    __shared__ double a[2][256], b[2][256], c[2][256];
    __shared__ double AL[8][256], BE[8][256];
    const int x = threadIdx.x;
    double invd = 1.0;
    // m=1 first, m=0 last (Woodbury PCR below reuses m=0's AL/BE).
    for (int mm = 0; mm < 2; mm++) {
        const int m = 1 - mm;
        double ai, bi, ci;
        if (m == 0) {
            ai = (x == 0) ? 0.0 : -cc;
            bi = 1.0 + 2.0 * cc;
            ci = (x == 255) ? 0.0 : -cc;
        } else {
            if (x == 0 || x == 255) { ai = 0.0; bi = 1.0; ci = 0.0; }
            else {
                ai = (x == 1) ? 0.0 : -cc;
                bi = 1.0 + 2.0 * cc;
                ci = (x == 254) ? 0.0 : -cc;
            }
        }
        int cur = 0;
        a[0][x] = ai; b[0][x] = bi; c[0][x] = ci;
        __syncthreads();
        for (int l = 0; l < 8; l++) {
            int s = 1 << l;
            int xm = (x - s < 0) ? 0 : x - s;
            int xp = (x + s > 255) ? 255 : x + s;
            double al = a[cur][x] / b[cur][xm];   // exactly 0 when x-s<0
            double be = c[cur][x] / b[cur][xp];   // exactly 0 when x+s>255
            AL[l][x] = al; BE[l][x] = be;
            double an = -al * a[cur][xm];
            double cn = -be * c[cur][xp];
            double bn = b[cur][x] - al * c[cur][xm] - be * a[cur][xp];
            a[1 - cur][x] = an; b[1 - cur][x] = bn; c[1 - cur][x] = cn;
            __syncthreads();
            cur ^= 1;
        }
        invd = 1.0 / b[cur][x];
        __syncthreads();   // AL/BE complete before cross-x reads
        float* Cr = C + (size_t)m * 22 * 256;
#pragma unroll
        for (int p = 0; p < 4; p++) {
            int s = 1 << (2 * p), s2 = 2 * s;
            double a0 = AL[2*p][x],   b0 = BE[2*p][x];
            double a1 = AL[2*p+1][x], b1 = BE[2*p+1][x];
            double am = (x - s2 >= 0) ? AL[2*p][x - s2] : 0.0;
            double bm = (x - s2 >= 0) ? BE[2*p][x - s2] : 0.0;
            double ap = (x + s2 < 256) ? AL[2*p][x + s2] : 0.0;
            double bq = (x + s2 < 256) ? BE[2*p][x + s2] : 0.0;
            double A3 = -a1 * am;
            double A2 = a1;
            double A1 = a0 - a1 * bm;
            double B1 = b0 - b1 * ap;
            double B2 = b1;
            double B3 = -b1 * bq;
            if (p < 3) {
                Cr[(p*6+0)*256 + x] = (float)A3;
                Cr[(p*6+1)*256 + x] = (float)A2;
                Cr[(p*6+2)*256 + x] = (float)A1;
                Cr[(p*6+3)*256 + x] = (float)B1;
                Cr[(p*6+4)*256 + x] = (float)B2;
                Cr[(p*6+5)*256 + x] = (float)B3;
            } else {   // s=64: offsets fold mod 256 -> 3 lane groups
                Cr[18*256 + x] = (float)(A1 + B3);   // lane -16
                Cr[19*256 + x] = (float)(A2 + B2);   // lane +-32
                Cr[20*256 + x] = (float)(A3 + B1);   // lane +16
            }
        }
        Cr[21*256 + x] = (float)invd;
        __syncthreads();
    }
    // Woodbury columns via fp64 PCR on m=0 coefficients, two RHS at once.
    {
        int cur = 0;
        a[0][x] = (x == 0) ? -cc : 0.0;     // r1 = -c e0
        b[0][x] = (x == 255) ? -cc : 0.0;   // r2 = -c e255
        __syncthreads();
        for (int l = 0; l < 8; l++) {
            int s = 1 << l;
            int xm = (x - s < 0) ? 0 : x - s;
            int xp = (x + s > 255) ? 255 : x + s;
            double n1 = a[cur][x] - AL[l][x] * a[cur][xm] - BE[l][x] * a[cur][xp];
            double n2 = b[cur][x] - AL[l][x] * b[cur][xm] - BE[l][x] * b[cur][xp];
            a[1 - cur][x] = n1; b[1 - cur][x] = n2;
            __syncthreads();
            cur ^= 1;
        }
        double t1 = a[cur][x] * invd;
        double t2 = b[cur][x] * invd;
        c[0][x] = t1; c[1][x] = t2;
        __syncthreads();
        double K00 = 1.0 + c[0][254], K01 = c[1][254];
        double K10 = c[0][1],         K11 = 1.0 + c[1][1];
        double idet = 1.0 / (K00 * K11 - K01 * K10);
        double Ki00 = K11 * idet, Ki01 = -K01 * idet;
        double Ki10 = -K10 * idet, Ki11 = K00 * idet;
        C[44 * 256 + x] = (float)(t1 * Ki00 + t2 * Ki10);
        C[45 * 256 + x] = (float)(t1 * Ki01 + t2 * Ki11);
    }
}

// ===================== split scan kernel =====================
__device__ __forceinline__ float bp(int idx, float v) {
    return __builtin_bit_cast(float,
        __builtin_amdgcn_ds_bpermute(idx, __builtin_bit_cast(int, v)));
}

// grid (128, 2), 384 threads = 6 waves; lane L owns x = 4L..4L+3.
// role 0: nodes {1(ic), 2*(shadow f2 -> stores ch0=dW), 3, 5, 7, 10}
// role 1: nodes {2, 4, 6, 8, 9, 11}
// Consumers lag producers by KLAG steps; ring depth RING=2*KLAG; barrier
// every KLAG iterations only.
__global__ __launch_bounds__(384, 1) void k_split(const float* __restrict__ W,
        const float* __restrict__ U0, const float* __restrict__ C,
        float* __restrict__ out) {
    const int b = blockIdx.x;
    const int role = blockIdx.y;
    const int tid = threadIdx.x;
    const int wv = tid >> 6;
    const int L = tid & 63;

    const bool isIC = (role == 0 && wv == 0);
    const bool isProd = (wv < 2);
    const bool storeDW = (role == 0 && wv == 1);
    bool needW;
    int storeCh, pubPlane, fmode, pmode;
    if (role == 0) {
        const int SC[6] = {1, 0, 3, 5, 7, 10};
        const int FM[6] = {-1, -1, 0, 1, 2, 3};   // p0 | dW*p0 | p1*p0 | p0^2
        storeCh = SC[wv]; fmode = FM[wv];
        needW = (wv == 1 || wv == 3);
        pubPlane = (wv == 0) ? 0 : ((wv == 1) ? 1 : -1);
        pmode = (wv == 0) ? 0 : 1;                // ic: d=y ; 2*: d=y+dW*dt
    } else {
        const int SC[6] = {2, 4, 6, 8, 9, 11};
        const int FM[6] = {-1, -1, 3, 4, 1, 2};   // p0^2 | p0^3 | dW*p0 | p1*p0
        storeCh = SC[wv]; fmode = FM[wv];
        needW = (wv <= 1 || wv == 4);
        pubPlane = (wv <= 1) ? wv : -1;
        pmode = (wv == 0) ? 1 : 2;                // 2: dW ; 4: dW^2
    }
    const int mat = isIC ? 1 : 0;

    // ---- fused-stage coefficients into registers (negated for fmaf) ----
    const float* Cm = C + (size_t)mat * 22 * 256;
    float ncf[21][4], ivd4[4], npk0[4], npk1[4];
#pragma unroll
    for (int r = 0; r < 21; r++) {
        f4 v = *(const f4*)&Cm[r * 256 + 4 * L];
#pragma unroll
        for (int q = 0; q < 4; q++) ncf[r][q] = -v[q];
    }
    {
        f4 vd = *(const f4*)&Cm[21 * 256 + 4 * L];
        f4 p0 = *(const f4*)&C[44 * 256 + 4 * L];
        f4 p1 = *(const f4*)&C[45 * 256 + 4 * L];
#pragma unroll
        for (int q = 0; q < 4; q++) { ivd4[q] = vd[q]; npk0[q] = -p0[q]; npk1[q] = -p1[q]; }
    }

    __shared__ f4 ring[RING][2][64];   // 32 KB

    // ---- state init + t=0 output row ----
    float y[4] = {0.f, 0.f, 0.f, 0.f};
    if (isIC) {
        f4 u0 = *(const f4*)&U0[b * 256 + 4 * L];
#pragma unroll
        for (int q = 0; q < 4; q++) y[q] = u0[q];
    }
    {
        size_t ob = ((size_t)b * 200) * 3072 + storeCh;
#pragma unroll
        for (int q = 0; q < 4; q++) out[ob + (4 * L + q) * 12] = isIC ? y[q] : 0.f;
    }
    float wprev[4] = {0,0,0,0}, wcur[4] = {0,0,0,0}, wnxt[4] = {0,0,0,0};
    if (needW) {
        f4 w0 = *(const f4*)&W[((size_t)b * 200 + 0) * 256 + 4 * L];
        f4 w1 = *(const f4*)&W[((size_t)b * 200 + 1) * 256 + 4 * L];
#pragma unroll
        for (int q = 0; q < 4; q++) { wprev[q] = w0[q]; wcur[q] = w1[q]; }
    }
    __syncthreads();

    for (int j = 1; j <= 199 + KLAG; j++) {
        const int t = isProd ? j : (j - KLAG);
        if (t >= 1 && t <= 199) {
            float dwv[4] = {0,0,0,0};
            if (needW) {
#pragma unroll
                for (int q = 0; q < 4; q++) dwv[q] = (wcur[q] - wprev[q]) * IDTF;
                if (t <= 198) {
                    f4 wn = *(const f4*)&W[((size_t)b * 200 + t + 1) * 256 + 4 * L];
#pragma unroll
                    for (int q = 0; q < 4; q++) wnxt[q] = wn[q];
                }
            }
            // ---- forcing ----
            float d[4];
            if (isProd) {
                if (pmode == 0) {
#pragma unroll
                    for (int q = 0; q < 4; q++) d[q] = y[q];
                } else if (pmode == 1) {
#pragma unroll
                    for (int q = 0; q < 4; q++) d[q] = fmaf(dwv[q], DTF, y[q]);
                } else {
#pragma unroll
                    for (int q = 0; q < 4; q++) d[q] = fmaf(dwv[q] * dwv[q], DTF, y[q]);
                }
            } else {
                f4 u = ring[t & (RING - 1)][0][L];
                f4 v = (fmode == 2) ? ring[t & (RING - 1)][1][L] : u;
#pragma unroll
                for (int q = 0; q < 4; q++) {
                    float fq;
                    if (fmode == 0)      fq = u[q];
                    else if (fmode == 1) fq = dwv[q] * u[q];
                    else if (fmode == 2) fq = v[q] * u[q];
                    else if (fmode == 3) fq = u[q] * u[q];
                    else                 fq = u[q] * u[q] * u[q];
                    d[q] = fmaf(fq, DTF, y[q]);
                }
            }
            // ---- PCR solve: 4 fused bpermute stages ----
            {   // stage 0 (s=1,2): neighbor lanes, 12-elem window, results in r[]
                int im = ((L + 63) & 63) << 2, ip = ((L + 1) & 63) << 2;
                float w[12], r[4];
                w[4] = d[0]; w[5] = d[1]; w[6] = d[2]; w[7] = d[3];
#pragma unroll
                for (int q = 0; q < 4; q++) { w[q] = bp(im, d[q]); w[8 + q] = bp(ip, d[q]); }
#pragma unroll
                for (int q = 0; q < 4; q++) {
                    float t0 = fmaf(ncf[0][q], w[q + 1], fmaf(ncf[1][q], w[q + 2], w[4 + q]));
                    float t1 = fmaf(ncf[2][q], w[q + 3], fmaf(ncf[3][q], w[q + 5], t0));
                    r[q] = fmaf(ncf[4][q], w[q + 6], fmaf(ncf[5][q], w[q + 7], t1));
                }
                d[0] = r[0]; d[1] = r[1]; d[2] = r[2]; d[3] = r[3];
            }
#pragma unroll
            for (int st = 1; st < 3; st++) {   // stage1: s=4 (lanes 1,2,3); stage2: s=16 (4,8,12)
                const int u = (st == 1) ? 1 : 4;
                int im1 = ((L - u) & 63) << 2, im2 = ((L - 2*u) & 63) << 2, im3 = ((L - 3*u) & 63) << 2;
                int ip1 = ((L + u) & 63) << 2, ip2 = ((L + 2*u) & 63) << 2, ip3 = ((L + 3*u) & 63) << 2;
                float m1[4], m2[4], m3[4], q1[4], q2[4], q3[4];
#pragma unroll
                for (int q = 0; q < 4; q++) {
                    m1[q] = bp(im1, d[q]); m2[q] = bp(im2, d[q]); m3[q] = bp(im3, d[q]);
                    q1[q] = bp(ip1, d[q]); q2[q] = bp(ip2, d[q]); q3[q] = bp(ip3, d[q]);
                }
                const int r0 = st * 6;
#pragma unroll
                for (int q = 0; q < 4; q++) {
                    float t0 = fmaf(ncf[r0+0][q], m3[q], fmaf(ncf[r0+1][q], m2[q], d[q]));
                    float t1 = fmaf(ncf[r0+2][q], m1[q], fmaf(ncf[r0+3][q], q1[q], t0));
                    d[q]    = fmaf(ncf[r0+4][q], q2[q], fmaf(ncf[r0+5][q], q3[q], t1));
                }
            }
            {   // stage 3 (s=64,128): lanes -16(M), +-32(Cc), +16(P), combined coeffs
                int imM = ((L + 48) & 63) << 2, ipP = ((L + 16) & 63) << 2, ipC = ((L + 32) & 63) << 2;
                float M[4], P[4], Cc[4];
#pragma unroll
                for (int q = 0; q < 4; q++) { M[q] = bp(imM, d[q]); P[q] = bp(ipP, d[q]); Cc[q] = bp(ipC, d[q]); }
#pragma unroll
                for (int q = 0; q < 4; q++)
                    d[q] = fmaf(ncf[18][q], M[q], fmaf(ncf[19][q], Cc[q], fmaf(ncf[20][q], P[q], d[q])));
            }
#pragma unroll
            for (int q = 0; q < 4; q++) d[q] *= ivd4[q];
            if (!isIC) {   // periodic Woodbury rank-2 correction
                float s1 = __shfl(d[2], 63, 64);   // w[254] = 4*63+2
                float s2 = __shfl(d[1], 0, 64);    // w[1]
#pragma unroll
                for (int q = 0; q < 4; q++)
                    d[q] = fmaf(npk0[q], s1, fmaf(npk1[q], s2, d[q]));
            }
#pragma unroll
            for (int q = 0; q < 4; q++) y[q] = d[q];
            // ---- publish / store ----
            if (pubPlane >= 0) {
                f4 pk; pk[0] = y[0]; pk[1] = y[1]; pk[2] = y[2]; pk[3] = y[3];
                ring[t & (RING - 1)][pubPlane][L] = pk;
            }
            {
                size_t ob = ((size_t)b * 200 + t) * 3072 + storeCh;
#pragma unroll
                for (int q = 0; q < 4; q++)
                    out[ob + (4 * L + q) * 12] = storeDW ? dwv[q] : y[q];
            }
            if (needW && t <= 198) {
#pragma unroll
                for (int q = 0; q < 4; q++) { wprev[q] = wcur[q]; wcur[q] = wnxt[q]; }
            }
        }
        if ((j & (KLAG - 1)) == 0) __syncthreads();
    }
}

// ===================== launch =====================
extern "C" void kernel_launch(void* const* d_in, const int* in_sizes, int n_in,
                              void* d_out, int out_size, void* d_ws, size_t ws_size,
                              hipStream_t stream) {
    const float* W = (const float*)d_in[0];
    const float* U0 = (const float*)d_in[1];
    float* out = (float*)d_out;
    float* C = (float*)d_ws;   // 46*256 floats = 47 KB

    k_pcr<<<1, 256, 0, stream>>>(C);
    k_split<<<dim3(128, 2), 384, 0, stream>>>(W, U0, C, out);
}

// Round 8
// 413.484 us; speedup vs baseline: 5.5343x; 1.0243x over previous
//
#include <hip/hip_runtime.h>

#define IDTF 199.0f
#define DTF  (1.0f/199.0f)
#define KLAG 8
#define RING 16

typedef float f4 __attribute__((ext_vector_type(4)));

// ===================== PCR coefficient precompute (fp64) =====================
// B = I - c*A. m=0: truncated tridiag (periodic base; corners via Woodbury).
// m=1: Dirichlet blockdiag(1, S, 1).
// Fused 2-level PCR coefficients. C layout (rows of 256 floats), per m at
// m*22: rows p*6+{0..5} = A3,A2,A1,B1,B2,B3 for stage p in {0,1,2} (s=1,4,16);
// rows 18,19,20 = combined stage-3 (s=64): cM(-16 lanes), cC(+-32), cP(+16);
// row 21 = invd. Rows 44,45: Woodbury (T^-1 U) K^-1 columns.
__global__ void k_pcr(float* __restrict__ C) {
    const double cc = 65025.0 / 199.0;   // eps*dt/dx^2 = 255^2/199
    __shared__ double a[2][256], b[2][256], c[2][256];
    __shared__ double AL[8][256], BE[8][256];
    const int x = threadIdx.x;
    double invd = 1.0;
    // m=1 first, m=0 last (Woodbury PCR below reuses m=0's AL/BE).
    for (int mm = 0; mm < 2; mm++) {
        const int m = 1 - mm;
        double ai, bi, ci;
        if (m == 0) {
            ai = (x == 0) ? 0.0 : -cc;
            bi = 1.0 + 2.0 * cc;
            ci = (x == 255) ? 0.0 : -cc;
        } else {
            if (x == 0 || x == 255) { ai = 0.0; bi = 1.0; ci = 0.0; }
            else {
                ai = (x == 1) ? 0.0 : -cc;
                bi = 1.0 + 2.0 * cc;
                ci = (x == 254) ? 0.0 : -cc;
            }
        }
        int cur = 0;
        a[0][x] = ai; b[0][x] = bi; c[0][x] = ci;
        __syncthreads();
        for (int l = 0; l < 8; l++) {
            int s = 1 << l;
            int xm = (x - s < 0) ? 0 : x - s;
            int xp = (x + s > 255) ? 255 : x + s;
            double al = a[cur][x] / b[cur][xm];   // exactly 0 when x-s<0
            double be = c[cur][x] / b[cur][xp];   // exactly 0 when x+s>255
            AL[l][x] = al; BE[l][x] = be;
            double an = -al * a[cur][xm];
            double cn = -be * c[cur][xp];
            double bn = b[cur][x] - al * c[cur][xm] - be * a[cur][xp];
            a[1 - cur][x] = an; b[1 - cur][x] = bn; c[1 - cur][x] = cn;
            __syncthreads();
            cur ^= 1;
        }
        invd = 1.0 / b[cur][x];
        __syncthreads();   // AL/BE complete before cross-x reads
        float* Cr = C + (size_t)m * 22 * 256;
#pragma unroll
        for (int p = 0; p < 4; p++) {
            int s = 1 << (2 * p), s2 = 2 * s;
            double a0 = AL[2*p][x],   b0 = BE[2*p][x];
            double a1 = AL[2*p+1][x], b1 = BE[2*p+1][x];
            double am = (x - s2 >= 0) ? AL[2*p][x - s2] : 0.0;
            double bm = (x - s2 >= 0) ? BE[2*p][x - s2] : 0.0;
            double ap = (x + s2 < 256) ? AL[2*p][x + s2] : 0.0;
            double bq = (x + s2 < 256) ? BE[2*p][x + s2] : 0.0;
            double A3 = -a1 * am;
            double A2 = a1;
            double A1 = a0 - a1 * bm;
            double B1 = b0 - b1 * ap;
            double B2 = b1;
            double B3 = -b1 * bq;
            if (p < 3) {
                Cr[(p*6+0)*256 + x] = (float)A3;
                Cr[(p*6+1)*256 + x] = (float)A2;
                Cr[(p*6+2)*256 + x] = (float)A1;
                Cr[(p*6+3)*256 + x] = (float)B1;
                Cr[(p*6+4)*256 + x] = (float)B2;
                Cr[(p*6+5)*256 + x] = (float)B3;
            } else {   // s=64: offsets fold mod 256 -> 3 lane groups
                Cr[18*256 + x] = (float)(A1 + B3);   // lane -16
                Cr[19*256 + x] = (float)(A2 + B2);   // lane +-32
                Cr[20*256 + x] = (float)(A3 + B1);   // lane +16
            }
        }
        Cr[21*256 + x] = (float)invd;
        __syncthreads();
    }
    // Woodbury columns via fp64 PCR on m=0 coefficients, two RHS at once.
    {
        int cur = 0;
        a[0][x] = (x == 0) ? -cc : 0.0;     // r1 = -c e0
        b[0][x] = (x == 255) ? -cc : 0.0;   // r2 = -c e255
        __syncthreads();
        for (int l = 0; l < 8; l++) {
            int s = 1 << l;
            int xm = (x - s < 0) ? 0 : x - s;
            int xp = (x + s > 255) ? 255 : x + s;
            double n1 = a[cur][x] - AL[l][x] * a[cur][xm] - BE[l][x] * a[cur][xp];
            double n2 = b[cur][x] - AL[l][x] * b[cur][xm] - BE[l][x] * b[cur][xp];
            a[1 - cur][x] = n1; b[1 - cur][x] = n2;
            __syncthreads();
            cur ^= 1;
        }
        double t1 = a[cur][x] * invd;
        double t2 = b[cur][x] * invd;
        c[0][x] = t1; c[1][x] = t2;
        __syncthreads();
        double K00 = 1.0 + c[0][254], K01 = c[1][254];
        double K10 = c[0][1],         K11 = 1.0 + c[1][1];
        double idet = 1.0 / (K00 * K11 - K01 * K10);
        double Ki00 = K11 * idet, Ki01 = -K01 * idet;
        double Ki10 = -K10 * idet, Ki11 = K00 * idet;
        C[44 * 256 + x] = (float)(t1 * Ki00 + t2 * Ki10);
        C[45 * 256 + x] = (float)(t1 * Ki01 + t2 * Ki11);
    }
}

// ===================== split scan kernel =====================
// grid(256); bid decode pairs the two role-blocks of a batch onto the SAME
// XCD (ids differ by 8) so their interleaved output writes merge in one L2.
// 384 threads = 6 waves; lane L owns x = 4L..4L+3.
// role 0: nodes {1(ic), 2*(shadow f2 -> stores ch0=dW), 3, 5, 7, 10}
// role 1: nodes {2, 4, 6, 8, 9, 11}
// Consumers lag producers by KLAG steps; ring depth RING=2*KLAG; barrier
// every KLAG iterations. All PCR exchanges via per-wave LDS scr (write_b128 +
// read_b128, wave_barrier fenced; per-wave DS pipe is in-order).
__global__ __launch_bounds__(384, 1) void k_split(const float* __restrict__ W,
        const float* __restrict__ U0, const float* __restrict__ C,
        float* __restrict__ out) {
    const int bid = blockIdx.x;
    const int role = (bid >> 3) & 1;
    const int b = (bid & 7) | ((bid >> 4) << 3);
    const int tid = threadIdx.x;
    const int wv = tid >> 6;
    const int L = tid & 63;

    const bool isIC = (role == 0 && wv == 0);
    const bool isProd = (wv < 2);
    const bool storeDW = (role == 0 && wv == 1);
    bool needW;
    int storeCh, pubPlane, fmode, pmode;
    if (role == 0) {
        const int SC[6] = {1, 0, 3, 5, 7, 10};
        const int FM[6] = {-1, -1, 0, 1, 2, 3};   // p0 | dW*p0 | p1*p0 | p0^2
        storeCh = SC[wv]; fmode = FM[wv];
        needW = (wv == 1 || wv == 3);
        pubPlane = (wv == 0) ? 0 : ((wv == 1) ? 1 : -1);
        pmode = (wv == 0) ? 0 : 1;                // ic: d=y ; 2*: d=y+dW*dt
    } else {
        const int SC[6] = {2, 4, 6, 8, 9, 11};
        const int FM[6] = {-1, -1, 3, 4, 1, 2};   // p0^2 | p0^3 | dW*p0 | p1*p0
        storeCh = SC[wv]; fmode = FM[wv];
        needW = (wv <= 1 || wv == 4);
        pubPlane = (wv <= 1) ? wv : -1;
        pmode = (wv == 0) ? 1 : 2;                // 2: dW ; 4: dW^2
    }
    const int mat = isIC ? 1 : 0;

    // ---- fused-stage coefficients into registers (negated for fmaf) ----
    const float* Cm = C + (size_t)mat * 22 * 256;
    float ncf[21][4], ivd4[4], npk0[4], npk1[4];
#pragma unroll
    for (int r = 0; r < 21; r++) {
        f4 v = *(const f4*)&Cm[r * 256 + 4 * L];
#pragma unroll
        for (int q = 0; q < 4; q++) ncf[r][q] = -v[q];
    }
    {
        f4 vd = *(const f4*)&Cm[21 * 256 + 4 * L];
        f4 p0 = *(const f4*)&C[44 * 256 + 4 * L];
        f4 p1 = *(const f4*)&C[45 * 256 + 4 * L];
#pragma unroll
        for (int q = 0; q < 4; q++) { ivd4[q] = vd[q]; npk0[q] = -p0[q]; npk1[q] = -p1[q]; }
    }

    __shared__ f4 ring[RING][2][64];   // 32 KB
    __shared__ f4 scr[6][64];          // 6 KB per-wave exchange scratch

    // ---- state init + t=0 output row ----
    float y[4] = {0.f, 0.f, 0.f, 0.f};
    if (isIC) {
        f4 u0 = *(const f4*)&U0[b * 256 + 4 * L];
#pragma unroll
        for (int q = 0; q < 4; q++) y[q] = u0[q];
    }
    {
        size_t ob = ((size_t)b * 200) * 3072 + storeCh;
#pragma unroll
        for (int q = 0; q < 4; q++) out[ob + (4 * L + q) * 12] = isIC ? y[q] : 0.f;
    }
    float wprev[4] = {0,0,0,0}, wcur[4] = {0,0,0,0}, wnxt[4] = {0,0,0,0};
    if (needW) {
        f4 w0 = *(const f4*)&W[((size_t)b * 200 + 0) * 256 + 4 * L];
        f4 w1 = *(const f4*)&W[((size_t)b * 200 + 1) * 256 + 4 * L];
#pragma unroll
        for (int q = 0; q < 4; q++) { wprev[q] = w0[q]; wcur[q] = w1[q]; }
    }
    __syncthreads();

    for (int j = 1; j <= 199 + KLAG; j++) {
        const int t = isProd ? j : (j - KLAG);
        if (t >= 1 && t <= 199) {
            float dwv[4] = {0,0,0,0};
            if (needW) {
#pragma unroll
                for (int q = 0; q < 4; q++) dwv[q] = (wcur[q] - wprev[q]) * IDTF;
                if (t <= 198) {
                    f4 wn = *(const f4*)&W[((size_t)b * 200 + t + 1) * 256 + 4 * L];
#pragma unroll
                    for (int q = 0; q < 4; q++) wnxt[q] = wn[q];
                }
            }
            // ---- forcing ----
            float d[4];
            if (isProd) {
                if (pmode == 0) {
#pragma unroll
                    for (int q = 0; q < 4; q++) d[q] = y[q];
                } else if (pmode == 1) {
#pragma unroll
                    for (int q = 0; q < 4; q++) d[q] = fmaf(dwv[q], DTF, y[q]);
                } else {
#pragma unroll
                    for (int q = 0; q < 4; q++) d[q] = fmaf(dwv[q] * dwv[q], DTF, y[q]);
                }
            } else {
                f4 u = ring[t & (RING - 1)][0][L];
                f4 v = (fmode == 2) ? ring[t & (RING - 1)][1][L] : u;
#pragma unroll
                for (int q = 0; q < 4; q++) {
                    float fq;
                    if (fmode == 0)      fq = u[q];
                    else if (fmode == 1) fq = dwv[q] * u[q];
                    else if (fmode == 2) fq = v[q] * u[q];
                    else if (fmode == 3) fq = u[q] * u[q];
                    else                 fq = u[q] * u[q] * u[q];
                    d[q] = fmaf(fq, DTF, y[q]);
                }
            }
            // ---- PCR solve: 4 fused stages, LDS b128 exchanges ----
            {   // stage 0 (s=1,2): lanes +-1, 12-elem window
                __builtin_amdgcn_wave_barrier();
                f4 pk; pk[0] = d[0]; pk[1] = d[1]; pk[2] = d[2]; pk[3] = d[3];
                scr[wv][L] = pk;
                __builtin_amdgcn_wave_barrier();
                f4 vm = scr[wv][(L + 63) & 63];
                f4 vp = scr[wv][(L + 1) & 63];
                __builtin_amdgcn_wave_barrier();
                float w[12], r[4];
                w[0]=vm[0]; w[1]=vm[1]; w[2]=vm[2]; w[3]=vm[3];
                w[4]=d[0];  w[5]=d[1];  w[6]=d[2];  w[7]=d[3];
                w[8]=vp[0]; w[9]=vp[1]; w[10]=vp[2]; w[11]=vp[3];
#pragma unroll
                for (int q = 0; q < 4; q++) {
                    float t0 = fmaf(ncf[0][q], w[q + 1], fmaf(ncf[1][q], w[q + 2], w[4 + q]));
                    float t1 = fmaf(ncf[2][q], w[q + 3], fmaf(ncf[3][q], w[q + 5], t0));
                    r[q] = fmaf(ncf[4][q], w[q + 6], fmaf(ncf[5][q], w[q + 7], t1));
                }
                d[0] = r[0]; d[1] = r[1]; d[2] = r[2]; d[3] = r[3];
            }
#pragma unroll
            for (int st = 1; st < 3; st++) {   // stage1: s=4 (lanes 1,2,3); stage2: s=16 (4,8,12)
                const int u = (st == 1) ? 1 : 4;
                __builtin_amdgcn_wave_barrier();
                f4 pk; pk[0] = d[0]; pk[1] = d[1]; pk[2] = d[2]; pk[3] = d[3];
                scr[wv][L] = pk;
                __builtin_amdgcn_wave_barrier();
                f4 m1 = scr[wv][(L - u) & 63];
                f4 m2 = scr[wv][(L - 2 * u) & 63];
                f4 m3 = scr[wv][(L - 3 * u) & 63];
                f4 q1 = scr[wv][(L + u) & 63];
                f4 q2 = scr[wv][(L + 2 * u) & 63];
                f4 q3 = scr[wv][(L + 3 * u) & 63];
                __builtin_amdgcn_wave_barrier();
                const int r0 = st * 6;
#pragma unroll
                for (int q = 0; q < 4; q++) {
                    float t0 = fmaf(ncf[r0+0][q], m3[q], fmaf(ncf[r0+1][q], m2[q], d[q]));
                    float t1 = fmaf(ncf[r0+2][q], m1[q], fmaf(ncf[r0+3][q], q1[q], t0));
                    d[q]    = fmaf(ncf[r0+4][q], q2[q], fmaf(ncf[r0+5][q], q3[q], t1));
                }
            }
            {   // stage 3 (s=64,128): lanes -16(M), +-32(C, folds to one), +16(P)
                __builtin_amdgcn_wave_barrier();
                f4 pk; pk[0] = d[0]; pk[1] = d[1]; pk[2] = d[2]; pk[3] = d[3];
                scr[wv][L] = pk;
                __builtin_amdgcn_wave_barrier();
                f4 vM = scr[wv][(L + 48) & 63];
                f4 vC = scr[wv][(L + 32) & 63];
                f4 vP = scr[wv][(L + 16) & 63];
                __builtin_amdgcn_wave_barrier();
#pragma unroll
                for (int q = 0; q < 4; q++)
                    d[q] = fmaf(ncf[18][q], vM[q], fmaf(ncf[19][q], vC[q], fmaf(ncf[20][q], vP[q], d[q])));
            }
#pragma unroll
            for (int q = 0; q < 4; q++) d[q] *= ivd4[q];
            if (!isIC) {   // periodic Woodbury rank-2 correction (VALU readlane)
                float s1 = __builtin_bit_cast(float,
                    __builtin_amdgcn_readlane(__builtin_bit_cast(int, d[2]), 63));  // w[254]
                float s2 = __builtin_bit_cast(float,
                    __builtin_amdgcn_readlane(__builtin_bit_cast(int, d[1]), 0));   // w[1]
#pragma unroll
                for (int q = 0; q < 4; q++)
                    d[q] = fmaf(npk0[q], s1, fmaf(npk1[q], s2, d[q]));
            }
#pragma unroll
            for (int q = 0; q < 4; q++) y[q] = d[q];
            // ---- publish / store ----
            if (pubPlane >= 0) {
                f4 pk; pk[0] = y[0]; pk[1] = y[1]; pk[2] = y[2]; pk[3] = y[3];
                ring[t & (RING - 1)][pubPlane][L] = pk;
            }
            {
                size_t ob = ((size_t)b * 200 + t) * 3072 + storeCh;
#pragma unroll
                for (int q = 0; q < 4; q++)
                    out[ob + (4 * L + q) * 12] = storeDW ? dwv[q] : y[q];
            }
            if (needW && t <= 198) {
#pragma unroll
                for (int q = 0; q < 4; q++) { wprev[q] = wcur[q]; wcur[q] = wnxt[q]; }
            }
        }
        if ((j & (KLAG - 1)) == 0) __syncthreads();
    }
}

// ===================== launch =====================
extern "C" void kernel_launch(void* const* d_in, const int* in_sizes, int n_in,
                              void* d_out, int out_size, void* d_ws, size_t ws_size,
                              hipStream_t stream) {
    const float* W = (const float*)d_in[0];
    const float* U0 = (const float*)d_in[1];
    float* out = (float*)d_out;
    float* C = (float*)d_ws;   // 46*256 floats = 47 KB

    k_pcr<<<1, 256, 0, stream>>>(C);
    k_split<<<dim3(256), 384, 0, stream>>>(W, U0, C, out);
}

// Round 9
// 282.926 us; speedup vs baseline: 8.0882x; 1.4615x over previous
//
#include <hip/hip_runtime.h>

#define IDTF 199.0f
#define DTF  (1.0f/199.0f)

typedef float f4 __attribute__((ext_vector_type(4)));

// ===================== PCR coefficient precompute (fp64) =====================
// B = I - c*A. m=0: truncated tridiag (periodic base; corners via Woodbury).
// m=1: Dirichlet blockdiag(1, S, 1).
// Fused 2-level PCR coefficients. C layout (rows of 256 floats), per m at
// m*22: rows p*6+{0..5} = A3,A2,A1,B1,B2,B3 for stage p in {0,1,2} (s=1,4,16);
// rows 18,19,20 = combined stage-3 (s=64): cM(-16 lanes), cC(+-32), cP(+16);
// row 21 = invd. Rows 44,45: Woodbury (T^-1 U) K^-1 columns.
__global__ void k_pcr(float* __restrict__ C) {
    const double cc = 65025.0 / 199.0;   // eps*dt/dx^2 = 255^2/199
    __shared__ double a[2][256], b[2][256], c[2][256];
    __shared__ double AL[8][256], BE[8][256];
    const int x = threadIdx.x;
    double invd = 1.0;
    // m=1 first, m=0 last (Woodbury PCR below reuses m=0's AL/BE).
    for (int mm = 0; mm < 2; mm++) {
        const int m = 1 - mm;
        double ai, bi, ci;
        if (m == 0) {
            ai = (x == 0) ? 0.0 : -cc;
            bi = 1.0 + 2.0 * cc;
            ci = (x == 255) ? 0.0 : -cc;
        } else {
            if (x == 0 || x == 255) { ai = 0.0; bi = 1.0; ci = 0.0; }
            else {
                ai = (x == 1) ? 0.0 : -cc;
                bi = 1.0 + 2.0 * cc;
                ci = (x == 254) ? 0.0 : -cc;
            }
        }
        int cur = 0;
        a[0][x] = ai; b[0][x] = bi; c[0][x] = ci;
        __syncthreads();
        for (int l = 0; l < 8; l++) {
            int s = 1 << l;
            int xm = (x - s < 0) ? 0 : x - s;
            int xp = (x + s > 255) ? 255 : x + s;
            double al = a[cur][x] / b[cur][xm];   // exactly 0 when x-s<0
            double be = c[cur][x] / b[cur][xp];   // exactly 0 when x+s>255
            AL[l][x] = al; BE[l][x] = be;
            double an = -al * a[cur][xm];
            double cn = -be * c[cur][xp];
            double bn = b[cur][x] - al * c[cur][xm] - be * a[cur][xp];
            a[1 - cur][x] = an; b[1 - cur][x] = bn; c[1 - cur][x] = cn;
            __syncthreads();
            cur ^= 1;
        }
        invd = 1.0 / b[cur][x];
        __syncthreads();   // AL/BE complete before cross-x reads
        float* Cr = C + (size_t)m * 22 * 256;
#pragma unroll
        for (int p = 0; p < 4; p++) {
            int s = 1 << (2 * p), s2 = 2 * s;
            double a0 = AL[2*p][x],   b0 = BE[2*p][x];
            double a1 = AL[2*p+1][x], b1 = BE[2*p+1][x];
            double am = (x - s2 >= 0) ? AL[2*p][x - s2] : 0.0;
            double bm = (x - s2 >= 0) ? BE[2*p][x - s2] : 0.0;
            double ap = (x + s2 < 256) ? AL[2*p][x + s2] : 0.0;
            double bq = (x + s2 < 256) ? BE[2*p][x + s2] : 0.0;
            double A3 = -a1 * am;
            double A2 = a1;
            double A1 = a0 - a1 * bm;
            double B1 = b0 - b1 * ap;
            double B2 = b1;
            double B3 = -b1 * bq;
            if (p < 3) {
                Cr[(p*6+0)*256 + x] = (float)A3;
                Cr[(p*6+1)*256 + x] = (float)A2;
                Cr[(p*6+2)*256 + x] = (float)A1;
                Cr[(p*6+3)*256 + x] = (float)B1;
                Cr[(p*6+4)*256 + x] = (float)B2;
                Cr[(p*6+5)*256 + x] = (float)B3;
            } else {   // s=64: offsets fold mod 256 -> 3 lane groups
                Cr[18*256 + x] = (float)(A1 + B3);   // lane -16
                Cr[19*256 + x] = (float)(A2 + B2);   // lane +-32
                Cr[20*256 + x] = (float)(A3 + B1);   // lane +16
            }
        }
        Cr[21*256 + x] = (float)invd;
        __syncthreads();
    }
    // Woodbury columns via fp64 PCR on m=0 coefficients, two RHS at once.
    {
        int cur = 0;
        a[0][x] = (x == 0) ? -cc : 0.0;     // r1 = -c e0
        b[0][x] = (x == 255) ? -cc : 0.0;   // r2 = -c e255
        __syncthreads();
        for (int l = 0; l < 8; l++) {
            int s = 1 << l;
            int xm = (x - s < 0) ? 0 : x - s;
            int xp = (x + s > 255) ? 255 : x + s;
            double n1 = a[cur][x] - AL[l][x] * a[cur][xm] - BE[l][x] * a[cur][xp];
            double n2 = b[cur][x] - AL[l][x] * b[cur][xm] - BE[l][x] * b[cur][xp];
            a[1 - cur][x] = n1; b[1 - cur][x] = n2;
            __syncthreads();
            cur ^= 1;
        }
        double t1 = a[cur][x] * invd;
        double t2 = b[cur][x] * invd;
        c[0][x] = t1; c[1][x] = t2;
        __syncthreads();
        double K00 = 1.0 + c[0][254], K01 = c[1][254];
        double K10 = c[0][1],         K11 = 1.0 + c[1][1];
        double idet = 1.0 / (K00 * K11 - K01 * K10);
        double Ki00 = K11 * idet, Ki01 = -K01 * idet;
        double Ki10 = -K10 * idet, Ki11 = K00 * idet;
        C[44 * 256 + x] = (float)(t1 * Ki00 + t2 * Ki10);
        C[45 * 256 + x] = (float)(t1 * Ki01 + t2 * Ki11);
    }
}

// ===================== split scan kernel =====================
// grid(256) = 128 batches x 2 roles (paired 8 apart -> same XCD).
// 448 threads = 7 waves; lane L owns x = 4L..4L+3.
// role0 waves: {ic, f2, f4*, n8, n9, n10, n11}; writer wave n10 stores ch8-11.
// role1 waves: {ic*, f2*(+dW), n4, n3, n5, n6, n7}; writers n3 (ch0-3) and
// n6 (ch4-7). All values go through a 4-slot LDS plane ring; writers lag 2
// steps and emit float4 stores (full-line coverage, no write amplification).
__global__ __launch_bounds__(448, 1) void k_split(const float* __restrict__ W,
        const float* __restrict__ U0, const float* __restrict__ C,
        float* __restrict__ out) {
    const int bid = blockIdx.x;
    const int role = (bid >> 3) & 1;
    const int b = (bid & 7) | ((bid >> 4) << 3);
    const int tid = threadIdx.x;
    const int wv = tid >> 6;
    const int L = tid & 63;

    // config tables [role][wv]
    static const signed char FMT[2][7] = {{-1,-1,-1, 4, 1, 3, 2},
                                          {-1,-1,-1, 0, 1, 3, 2}};
    static const signed char PAT[2][7] = {{ 0, 0, 0, 1, 1, 0, 2},
                                          { 0, 0, 0, 0, 0, 1, 1}};
    static const signed char PBT[2][7] = {{ 0, 0, 0, 0, 0, 0, 1},
                                          { 0, 0, 0, 0, 0, 0, 0}};
    static const signed char PUBT[2][7]= {{ 0, 1, 2, 3, 4, 5, 6},
                                          { 0, 1, 3, 4, 5, 6, 7}};
    static const signed char NWT[2][7] = {{ 0, 1, 1, 0, 1, 0, 0},
                                          { 0, 1, 1, 0, 1, 0, 0}};
    static const signed char WGT[2][7] = {{-1,-1,-1,-1,-1, 2,-1},
                                          {-1,-1,-1, 0,-1, 1,-1}};
    static const signed char WPT[2][7][4] = {
        {{0,0,0,0},{0,0,0,0},{0,0,0,0},{0,0,0,0},{0,0,0,0},{3,4,5,6},{0,0,0,0}},
        {{0,0,0,0},{0,0,0,0},{0,0,0,0},{2,0,1,4},{0,0,0,0},{3,5,6,7},{0,0,0,0}}};

    const bool isIC = (wv == 0);
    const bool isProd = (wv < 3);
    const int pmode = wv;                 // producers: 0=ic, 1=dW, 2=dW^2
    const int fmode = FMT[role][wv];
    const int pAi = PAT[role][wv], pBi = PBT[role][wv];
    const int pubP = PUBT[role][wv];
    const bool needW = NWT[role][wv];
    const int wgrp = WGT[role][wv];
    const int wpl0 = WPT[role][wv][0], wpl1 = WPT[role][wv][1];
    const int wpl2 = WPT[role][wv][2], wpl3 = WPT[role][wv][3];
    const bool pubDW = (role == 1 && wv == 1);
    const int mat = isIC ? 1 : 0;

    // ---- fused-stage coefficients into registers (negated for fmaf) ----
    const float* Cm = C + (size_t)mat * 22 * 256;
    float ncf[21][4], ivd4[4], npk0[4], npk1[4];
#pragma unroll
    for (int r = 0; r < 21; r++) {
        f4 v = *(const f4*)&Cm[r * 256 + 4 * L];
#pragma unroll
        for (int q = 0; q < 4; q++) ncf[r][q] = -v[q];
    }
    {
        f4 vd = *(const f4*)&Cm[21 * 256 + 4 * L];
        f4 p0 = *(const f4*)&C[44 * 256 + 4 * L];
        f4 p1 = *(const f4*)&C[45 * 256 + 4 * L];
#pragma unroll
        for (int q = 0; q < 4; q++) { ivd4[q] = vd[q]; npk0[q] = -p0[q]; npk1[q] = -p1[q]; }
    }

    __shared__ f4 ring[4][8][64];   // 32 KB: [slot][plane][lane]
    __shared__ f4 scr[7][64];       // 7 KB per-wave PCR exchange

    // ---- state init ----
    float y[4] = {0.f, 0.f, 0.f, 0.f};
    if (isIC) {
        f4 u0 = *(const f4*)&U0[b * 256 + 4 * L];
#pragma unroll
        for (int q = 0; q < 4; q++) y[q] = u0[q];
    }
    // t=0 output row (writer waves; float4 stores)
    if (wgrp >= 0) {
        f4* of4 = (f4*)out;
        size_t rb = (size_t)b * 200 * 768;
#pragma unroll
        for (int q = 0; q < 4; q++) {
            int x = 4 * L + q;
            f4 v = {0.f, 0.f, 0.f, 0.f};
            if (wgrp == 0) v[1] = U0[b * 256 + x];
            of4[rb + (size_t)x * 3 + wgrp] = v;
        }
    }
    float wprev[4] = {0,0,0,0}, wcur[4] = {0,0,0,0}, wnxt[4] = {0,0,0,0};
    if (needW) {
        f4 w0 = *(const f4*)&W[((size_t)b * 200 + 0) * 256 + 4 * L];
        f4 w1 = *(const f4*)&W[((size_t)b * 200 + 1) * 256 + 4 * L];
#pragma unroll
        for (int q = 0; q < 4; q++) { wprev[q] = w0[q]; wcur[q] = w1[q]; }
    }
    __syncthreads();

    // timeline: producers t=j (j<=199); consumers t=j-1 (2<=j<=200);
    // writers t=j-2 (3<=j<=201). Ring slot = t&3 (4 slots, lag<=2 safe).
    for (int j = 1; j <= 201; j++) {
        const int t = isProd ? j : (j - 1);
        const bool active = isProd ? (j <= 199) : (j >= 2 && j <= 200);
        if (active) {
            float dwv[4] = {0,0,0,0};
            if (needW) {
#pragma unroll
                for (int q = 0; q < 4; q++) dwv[q] = (wcur[q] - wprev[q]) * IDTF;
                if (t <= 198) {
                    f4 wn = *(const f4*)&W[((size_t)b * 200 + t + 1) * 256 + 4 * L];
#pragma unroll
                    for (int q = 0; q < 4; q++) wnxt[q] = wn[q];
                }
            }
            // ---- forcing ----
            float d[4];
            if (isProd) {
                if (pmode == 0) {
#pragma unroll
                    for (int q = 0; q < 4; q++) d[q] = y[q];
                } else if (pmode == 1) {
#pragma unroll
                    for (int q = 0; q < 4; q++) d[q] = fmaf(dwv[q], DTF, y[q]);
                } else {
#pragma unroll
                    for (int q = 0; q < 4; q++) d[q] = fmaf(dwv[q] * dwv[q], DTF, y[q]);
                }
            } else {
                f4 pa = ring[t & 3][pAi][L];
                f4 pb = (fmode == 2) ? ring[t & 3][pBi][L] : pa;
#pragma unroll
                for (int q = 0; q < 4; q++) {
                    float fq;
                    if (fmode == 0)      fq = pa[q];
                    else if (fmode == 1) fq = dwv[q] * pa[q];
                    else if (fmode == 2) fq = pb[q] * pa[q];
                    else if (fmode == 3) fq = pa[q] * pa[q];
                    else                 fq = pa[q] * pa[q] * pa[q];
                    d[q] = fmaf(fq, DTF, y[q]);
                }
            }
            // ---- PCR solve: 4 fused stages, per-wave LDS b128 exchanges ----
            {   // stage 0 (s=1,2): lanes +-1, 12-elem window
                __builtin_amdgcn_wave_barrier();
                f4 pk; pk[0] = d[0]; pk[1] = d[1]; pk[2] = d[2]; pk[3] = d[3];
                scr[wv][L] = pk;
                __builtin_amdgcn_wave_barrier();
                f4 vm = scr[wv][(L + 63) & 63];
                f4 vp = scr[wv][(L + 1) & 63];
                __builtin_amdgcn_wave_barrier();
                float w[12], r[4];
                w[0]=vm[0]; w[1]=vm[1]; w[2]=vm[2]; w[3]=vm[3];
                w[4]=d[0];  w[5]=d[1];  w[6]=d[2];  w[7]=d[3];
                w[8]=vp[0]; w[9]=vp[1]; w[10]=vp[2]; w[11]=vp[3];
#pragma unroll
                for (int q = 0; q < 4; q++) {
                    float t0 = fmaf(ncf[0][q], w[q + 1], fmaf(ncf[1][q], w[q + 2], w[4 + q]));
                    float t1 = fmaf(ncf[2][q], w[q + 3], fmaf(ncf[3][q], w[q + 5], t0));
                    r[q] = fmaf(ncf[4][q], w[q + 6], fmaf(ncf[5][q], w[q + 7], t1));
                }
                d[0] = r[0]; d[1] = r[1]; d[2] = r[2]; d[3] = r[3];
            }
#pragma unroll
            for (int st = 1; st < 3; st++) {   // stage1: s=4; stage2: s=16
                const int u = (st == 1) ? 1 : 4;
                __builtin_amdgcn_wave_barrier();
                f4 pk; pk[0] = d[0]; pk[1] = d[1]; pk[2] = d[2]; pk[3] = d[3];
                scr[wv][L] = pk;
                __builtin_amdgcn_wave_barrier();
                f4 m1 = scr[wv][(L - u) & 63];
                f4 m2 = scr[wv][(L - 2 * u) & 63];
                f4 m3 = scr[wv][(L - 3 * u) & 63];
                f4 q1 = scr[wv][(L + u) & 63];
                f4 q2 = scr[wv][(L + 2 * u) & 63];
                f4 q3 = scr[wv][(L + 3 * u) & 63];
                __builtin_amdgcn_wave_barrier();
                const int r0 = st * 6;
#pragma unroll
                for (int q = 0; q < 4; q++) {
                    float t0 = fmaf(ncf[r0+0][q], m3[q], fmaf(ncf[r0+1][q], m2[q], d[q]));
                    float t1 = fmaf(ncf[r0+2][q], m1[q], fmaf(ncf[r0+3][q], q1[q], t0));
                    d[q]    = fmaf(ncf[r0+4][q], q2[q], fmaf(ncf[r0+5][q], q3[q], t1));
                }
            }
            {   // stage 3 (s=64,128): lanes -16(M), +-32(C), +16(P)
                __builtin_amdgcn_wave_barrier();
                f4 pk; pk[0] = d[0]; pk[1] = d[1]; pk[2] = d[2]; pk[3] = d[3];
                scr[wv][L] = pk;
                __builtin_amdgcn_wave_barrier();
                f4 vM = scr[wv][(L + 48) & 63];
                f4 vC = scr[wv][(L + 32) & 63];
                f4 vP = scr[wv][(L + 16) & 63];
                __builtin_amdgcn_wave_barrier();
#pragma unroll
                for (int q = 0; q < 4; q++)
                    d[q] = fmaf(ncf[18][q], vM[q], fmaf(ncf[19][q], vC[q], fmaf(ncf[20][q], vP[q], d[q])));
            }
#pragma unroll
            for (int q = 0; q < 4; q++) d[q] *= ivd4[q];
            if (!isIC) {   // periodic Woodbury rank-2 correction (VALU readlane)
                float s1 = __builtin_bit_cast(float,
                    __builtin_amdgcn_readlane(__builtin_bit_cast(int, d[2]), 63));  // w[254]
                float s2 = __builtin_bit_cast(float,
                    __builtin_amdgcn_readlane(__builtin_bit_cast(int, d[1]), 0));   // w[1]
#pragma unroll
                for (int q = 0; q < 4; q++)
                    d[q] = fmaf(npk0[q], s1, fmaf(npk1[q], s2, d[q]));
            }
#pragma unroll
            for (int q = 0; q < 4; q++) y[q] = d[q];
            // ---- publish ----
            {
                f4 pk; pk[0] = y[0]; pk[1] = y[1]; pk[2] = y[2]; pk[3] = y[3];
                ring[t & 3][pubP][L] = pk;
            }
            if (pubDW) {
                f4 pk; pk[0] = dwv[0]; pk[1] = dwv[1]; pk[2] = dwv[2]; pk[3] = dwv[3];
                ring[t & 3][2][L] = pk;
            }
            if (needW && t <= 198) {
#pragma unroll
                for (int q = 0; q < 4; q++) { wprev[q] = wcur[q]; wcur[q] = wnxt[q]; }
            }
        }
        // ---- writer duty (lag 2): read 4 planes, transpose, float4 stores ----
        if (wgrp >= 0 && j >= 3) {
            const int tw = j - 2;
            const int s = tw & 3;
            f4 p0 = ring[s][wpl0][L];
            f4 p1 = ring[s][wpl1][L];
            f4 p2 = ring[s][wpl2][L];
            f4 p3 = ring[s][wpl3][L];
            f4* of4 = (f4*)out;
            size_t rb = ((size_t)b * 200 + tw) * 768;
#pragma unroll
            for (int q = 0; q < 4; q++) {
                f4 v; v[0] = p0[q]; v[1] = p1[q]; v[2] = p2[q]; v[3] = p3[q];
                of4[rb + (size_t)(4 * L + q) * 3 + wgrp] = v;
            }
        }
        __syncthreads();
    }
}

// ===================== launch =====================
extern "C" void kernel_launch(void* const* d_in, const int* in_sizes, int n_in,
                              void* d_out, int out_size, void* d_ws, size_t ws_size,
                              hipStream_t stream) {
    const float* W = (const float*)d_in[0];
    const float* U0 = (const float*)d_in[1];
    float* out = (float*)d_out;
    float* C = (float*)d_ws;   // 46*256 floats = 47 KB

    k_pcr<<<1, 256, 0, stream>>>(C);
    k_split<<<dim3(256), 448, 0, stream>>>(W, U0, C, out);
}